// Round 6
// baseline (597.848 us; speedup 1.0000x reference)
//
#include <hip/hip_runtime.h>

// HashEncoder forward, R9.
// R8 verdict: forced 16-deep MLP (volatile-asm loads, single vmcnt drain)
// changed NOTHING (397us, 4 structures all 396-402us) => enc is capped by a
// shared gather-request service rate (~14.5 req/cy/XCD ~ L2 tag pipe), not
// per-wave latency. Requests/point-level is the only lever:
//   table 6.0 (hash-structural floor: 4 aligned pairs + avg 2 odd singles)
//   input 0.56 -> 0.19 (R9: pre-pack input to SoA-pair {x0,y0,x1,y1}f4 +
//                       {z0,z1}f2; 3 coalesced loads = 24 req/wave vs 72)
//   dummy 0.03 -> 0     (R9: back to exec-masked odd loads, no dummies)
//   store 0.13          (NT float4)
// Predicted enc ~370us; if >=390, request model's last free term is dead and
// the kernel is at its structural roofline.
// Structure: 3-pass (per-level dispatch = per-XCD L2 table locality, R4
// proved fusion costs 9x FETCH). bf16 table keeps hashed level at 2MiB.

static constexpr uint32_t P1 = 2654435761u;
static constexpr uint32_t P2 = 805459861u;
static constexpr uint32_t NPARAMS = 7114752u;
static constexpr uint32_t HMASK = 524287u;

typedef float f32x4 __attribute__((ext_vector_type(4)));
typedef float f32x2 __attribute__((ext_vector_type(2)));

// ---------- pass 0a: table fp32 -> packed bf16x2 ----------
__device__ inline uint32_t bf16_bits(float f) {
    uint32_t u = __float_as_uint(f);
    return (u + 0x7FFFu + ((u >> 16) & 1u)) >> 16;
}

__global__ __launch_bounds__(256) void convert_bf16(
    const float* __restrict__ emb, uint32_t* __restrict__ tab)
{
    const uint32_t i = blockIdx.x * 256u + threadIdx.x;   // float4 index
    const float4 v = ((const float4*)emb)[i];
    uint2 o;
    o.x = bf16_bits(v.x) | (bf16_bits(v.y) << 16);
    o.y = bf16_bits(v.z) | (bf16_bits(v.w) << 16);
    ((uint2*)tab)[i] = o;
}

// ---------- pass 0b: input AoS 12B/pt -> SoA-pair (16B + 8B per pair) ----------
__global__ __launch_bounds__(256) void pack_input(
    const float* __restrict__ inp, float4* __restrict__ pA,
    float2* __restrict__ pB, int npairs)
{
    const uint32_t u = blockIdx.x * 256u + threadIdx.x;
    if (u >= (uint32_t)npairs) return;
    const float2* in2 = (const float2*)inp;
    const float2 ab = in2[3u * u + 0u];   // x0 y0
    const float2 cd = in2[3u * u + 1u];   // z0 x1
    const float2 ef = in2[3u * u + 2u];   // y1 z1
    const f32x4 a = {ab.x, ab.y, cd.y, ef.x};   // x0 y0 x1 y1
    const f32x2 b = {cd.x, ef.y};               // z0 z1
    __builtin_nontemporal_store(a, (f32x4*)&pA[u]);
    __builtin_nontemporal_store(b, (f32x2*)&pB[u]);
}

// ---------- pass 1: 2 points x 1 level per thread ----------
__global__ __launch_bounds__(256) void enc_level2(
    const float4* __restrict__ pA,      // {x0,y0,x1,y1} per pair (or null)
    const float2* __restrict__ pB,      // {z0,z1} per pair (or null)
    const float* __restrict__ inp,      // raw fallback
    const uint32_t* __restrict__ tab,   // packed bf16x2 per row
    float2* __restrict__ stage,         // [16][np]
    int npoints)
{
    const uint32_t l = blockIdx.y;
    const uint32_t u = blockIdx.x * 256u + threadIdx.x;   // point-pair index

    float xs[2], ys[2], zs[2];
    if (pA) {
        const float4 a = pA[u];         // fully coalesced 16B
        const float2 b = pB[u];         // fully coalesced 8B
        xs[0] = a.x; ys[0] = a.y; zs[0] = b.x;
        xs[1] = a.z; ys[1] = a.w; zs[1] = b.y;
    } else {
        const float2* in2 = (const float2*)inp;
        const float2 ab = in2[3u * u + 0u];
        const float2 cd = in2[3u * u + 1u];
        const float2 ef = in2[3u * u + 2u];
        xs[0] = ab.x; ys[0] = ab.y; zs[0] = cd.x;
        xs[1] = cd.y; ys[1] = ef.x; zs[1] = ef.y;
    }

    const uint32_t res = 16u << l;
    const float scale = (float)(res - 1u);

    uint32_t off;
    if (l >= 3u)      off = 299008u + (l - 3u) * 524288u;
    else if (l == 2u) off = 36864u;
    else if (l == 1u) off = 4096u;
    else              off = 0u;
    const bool hashed = (l >= 3u);
    const uint32_t s = 4u + (hashed ? 0u : l);

    float wx0[2], wx1[2], wyq[2][2], wzq[2][2];
    uint32_t idxA[2][4];
    bool gx_odd[2];
    uint32_t gxq[2];

    // ---- phase A: addresses + weights for both points ----
#pragma unroll
    for (int q = 0; q < 2; ++q) {
        const float x01 = (xs[q] + 1.0f) * 0.5f;
        const float y01 = (ys[q] + 1.0f) * 0.5f;
        const float z01 = (zs[q] + 1.0f) * 0.5f;
        const float posx = x01 * scale + 0.5f;
        const float posy = y01 * scale + 0.5f;
        const float posz = z01 * scale + 0.5f;
        const float fgx = floorf(posx), fgy = floorf(posy), fgz = floorf(posz);
        const float fx = posx - fgx, fy = posy - fgy, fz = posz - fgz;
        const uint32_t gx = (uint32_t)fgx, gy = (uint32_t)fgy, gz = (uint32_t)fgz;

        wx0[q] = 1.0f - fx; wx1[q] = fx;
        wyq[q][0] = 1.0f - fy; wyq[q][1] = fy;
        wzq[q][0] = 1.0f - fz; wzq[q][1] = fz;
        gxq[q] = gx;
        gx_odd[q] = (gx & 1u) != 0u;

        uint32_t yzc[4];
        if (hashed) {
            const uint32_t hy0 = gy * P1, hy1 = hy0 + P1;
            const uint32_t hz0 = gz * P2, hz1 = hz0 + P2;
            yzc[0] = hy0 ^ hz0; yzc[1] = hy1 ^ hz0;
            yzc[2] = hy0 ^ hz1; yzc[3] = hy1 ^ hz1;
        } else {
            const uint32_t dy0 = gy << s, dy1 = dy0 + (1u << s);
            const uint32_t dz0 = gz << (2u * s), dz1 = dz0 + (1u << (2u * s));
            yzc[0] = dy0 + dz0; yzc[1] = dy1 + dz0;
            yzc[2] = dy0 + dz1; yzc[3] = dy1 + dz1;
        }
#pragma unroll
        for (int c = 0; c < 4; ++c)
            idxA[q][c] = hashed ? ((gxq[q] ^ yzc[c]) & HMASK)
                                : (gxq[q] + yzc[c]);
    }

    // ---- phase B: all 8 aligned pair loads (both x-corners when gx even) ----
    uint2 pr[2][4];
#pragma unroll
    for (int q = 0; q < 2; ++q)
#pragma unroll
        for (int c = 0; c < 4; ++c)
            pr[q][c] = *(const uint2*)(tab + off + (idxA[q][c] & ~1u));

    // ---- phase C: odd-gx extra loads, exec-masked (no dummy requests) ----
    uint32_t vBo[2][4];
#pragma unroll
    for (int q = 0; q < 2; ++q) {
        if (gx_odd[q]) {
#pragma unroll
            for (int c = 0; c < 4; ++c) {
                const uint32_t idxB = hashed
                    ? (((gxq[q] + 1u) ^ (idxA[q][c] ^ gxq[q])) & HMASK)
                    : (idxA[q][c] + 1u);
                vBo[q][c] = tab[off + idxB];
            }
        }
    }

    // ---- phase D: weighted reduction ----
    f32x4 r;
#pragma unroll
    for (int q = 0; q < 2; ++q) {
        float sx = 0.0f, sy = 0.0f;
#pragma unroll
        for (int c = 0; c < 4; ++c) {
            const uint32_t lo = idxA[q][c] & 1u;
            const uint32_t vA  = lo ? pr[q][c].y : pr[q][c].x;
            const uint32_t vBe = lo ? pr[q][c].x : pr[q][c].y;  // idxA^1, valid iff gx even
            const uint32_t vB  = gx_odd[q] ? vBo[q][c] : vBe;
            const float wyz = wyq[q][c & 1] * wzq[q][c >> 1];
            const float eAx = __uint_as_float(vA << 16);
            const float eAy = __uint_as_float(vA & 0xFFFF0000u);
            const float eBx = __uint_as_float(vB << 16);
            const float eBy = __uint_as_float(vB & 0xFFFF0000u);
            sx = fmaf(wyz, fmaf(wx0[q], eAx, wx1[q] * eBx), sx);
            sy = fmaf(wyz, fmaf(wx0[q], eAy, wx1[q] * eBy), sy);
        }
        r[2 * q + 0] = sx;
        r[2 * q + 1] = sy;
    }

    // one nt float4 store: stage[l][2u .. 2u+1] (streaming; don't evict table)
    __builtin_nontemporal_store(r,
        (f32x4*)&((float4*)stage)[(size_t)l * ((uint32_t)npoints >> 1) + u]);
}

// ---------- pass 2: LDS-tiled transpose ----------
__global__ __launch_bounds__(256) void transpose_out(
    const float2* __restrict__ stage, float4* __restrict__ out4, int npoints)
{
    __shared__ float2 t[256][17];   // +1 pad: 2 lanes/bank on load phase (free)
    const uint32_t p0 = blockIdx.x * 256u;
    const uint32_t tid = threadIdx.x;

#pragma unroll
    for (int l = 0; l < 16; ++l) {
        const f32x2 v = __builtin_nontemporal_load(
            (const f32x2*)&stage[(size_t)l * (uint32_t)npoints + p0 + tid]);  // coalesced 2KB
        t[tid][l] = make_float2(v.x, v.y);
    }
    __syncthreads();

#pragma unroll
    for (int k = 0; k < 8; ++k) {
        const uint32_t f = (uint32_t)k * 256u + tid;
        const uint32_t p = f >> 3, c = f & 7u;
        const float2 a = t[p][2u * c];
        const float2 b = t[p][2u * c + 1u];
        const f32x4 v = {a.x, a.y, b.x, b.y};
        __builtin_nontemporal_store(v,
            (f32x4*)&out4[(size_t)(p0 + p) * 8u + c]);                        // coalesced 4KB
    }
}

// ---------- fallback: single-pass (R1) ----------
__global__ __launch_bounds__(256) void hashenc_fwd(
    const float* __restrict__ inp, const float* __restrict__ emb,
    float* __restrict__ out, int npoints)
{
    const uint32_t tid = blockIdx.x * 256u + threadIdx.x;
    const uint32_t p = tid >> 4, l = tid & 15u;
    if (p >= (uint32_t)npoints) return;
    const float x01 = (inp[p * 3u + 0u] + 1.0f) * 0.5f;
    const float y01 = (inp[p * 3u + 1u] + 1.0f) * 0.5f;
    const float z01 = (inp[p * 3u + 2u] + 1.0f) * 0.5f;
    const uint32_t res = 16u << l;
    const float scale = (float)(res - 1u);
    const float posx = x01 * scale + 0.5f, posy = y01 * scale + 0.5f, posz = z01 * scale + 0.5f;
    const float fgx = floorf(posx), fgy = floorf(posy), fgz = floorf(posz);
    const float fx = posx - fgx, fy = posy - fgy, fz = posz - fgz;
    const uint32_t gx = (uint32_t)fgx, gy = (uint32_t)fgy, gz = (uint32_t)fgz;
    uint32_t off;
    if (l >= 3u)      off = 299008u + (l - 3u) * 524288u;
    else if (l == 2u) off = 36864u;
    else if (l == 1u) off = 4096u;
    else              off = 0u;
    const bool hashed = (l >= 3u);
    const uint32_t s = 4u + (hashed ? 0u : l);
    const float wx[2] = {1.0f - fx, fx}, wy[2] = {1.0f - fy, fy}, wz[2] = {1.0f - fz, fz};
    float2 g[8]; float w[8];
#pragma unroll
    for (int c = 0; c < 8; ++c) {
        const uint32_t bx = (uint32_t)c & 1u, by = ((uint32_t)c >> 1) & 1u, bz = ((uint32_t)c >> 2) & 1u;
        const uint32_t cx = gx + bx, cy = gy + by, cz = gz + bz;
        const uint32_t hidx = (cx ^ (cy * P1) ^ (cz * P2)) & HMASK;
        const uint32_t didx = cx + (cy << s) + (cz << (2u * s));
        const uint32_t idx  = hashed ? hidx : didx;
        w[c] = wx[bx] * wy[by] * wz[bz];
        g[c] = *(const float2*)(emb + 2u * (off + idx));
    }
    float sx = 0.0f, sy = 0.0f;
#pragma unroll
    for (int c = 0; c < 8; ++c) { sx = fmaf(w[c], g[c].x, sx); sy = fmaf(w[c], g[c].y, sy); }
    *(float2*)(out + (size_t)p * 32u + (size_t)l * 2u) = make_float2(sx, sy);
}

extern "C" void kernel_launch(void* const* d_in, const int* in_sizes, int n_in,
                              void* d_out, int out_size, void* d_ws, size_t ws_size,
                              hipStream_t stream) {
    const float* inp = (const float*)d_in[0];
    const float* emb = (const float*)d_in[1];
    float* out = (float*)d_out;
    const int npoints = in_sizes[0] / 3;
    const int npairs = npoints / 2;

    const size_t tab_bytes   = (size_t)NPARAMS * 4u;
    const size_t stage_bytes = (size_t)npoints * 16u * 8u;
    const size_t pA_bytes    = (size_t)npairs * 16u;
    const size_t pB_bytes    = (size_t)npairs * 8u;
    const size_t need_base   = tab_bytes + stage_bytes;
    const size_t need_pack   = need_base + pA_bytes + pB_bytes;

    if (ws_size >= need_base && (npoints & 511) == 0) {
        uint32_t* tab  = (uint32_t*)d_ws;
        float2* stage  = (float2*)((char*)d_ws + tab_bytes);
        float4* pA = nullptr;
        float2* pB = nullptr;

        const int conv_units = (int)(NPARAMS * 2u / 4u);
        convert_bf16<<<(conv_units + 255) / 256, 256, 0, stream>>>(emb, tab);

        if (ws_size >= need_pack) {
            pA = (float4*)((char*)d_ws + need_base);
            pB = (float2*)((char*)d_ws + need_base + pA_bytes);
            pack_input<<<(npairs + 255) / 256, 256, 0, stream>>>(inp, pA, pB, npairs);
        }

        dim3 g1(npoints / 512, 16);
        enc_level2<<<g1, 256, 0, stream>>>(pA, pB, inp, tab, stage, npoints);

        transpose_out<<<npoints / 256, 256, 0, stream>>>(stage, (float4*)out, npoints);
    } else {
        const int total = npoints * 16;
        hashenc_fwd<<<(total + 255) / 256, 256, 0, stream>>>(inp, emb, out, npoints);
    }
}